// Round 7
// baseline (211.109 us; speedup 1.0000x reference)
//
#include <hip/hip_runtime.h>

// YOLO loss. R6: R1 (strided, occ 50%) and R2 (LDS-staged coalesced, occ 27%)
// both hit 68-70us @16% HBM, VALU<=15% => ~65% stall, barrier/latency-bound,
// NOT transaction-bound. New structure: 5 threads per cell (q=0..4),
// elementwise streaming (tc addr = 16*T exactly linear; pred as dense 24B-
// stride float2), tiny 5.4KB LDS only to pass p[0..9] to the q==0 lane for
// box math. 640-thr blocks = 128 cells exact, occupancy cap 93%, 1 barrier.
// ws layout: double acc[64][5] (2560 B) | int flag (at byte 2560)
constexpr int NSLOTS = 64;

// --- Kernel 1: zero accumulators + detect has_object_map encoding -----------
// JAX bool may arrive as uint8, int32, or float32. Classify first dwords:
// all in {0,1} -> int32 (flag=1); all in {0,0x3f800000} -> f32 (flag=2);
// else packed uint8 (flag=0).
__global__ void yl_detect_zero(const unsigned int* __restrict__ hmap,
                               double* __restrict__ acc,
                               int* __restrict__ flag, int bound) {
    __shared__ int ok[2];
    const int t = threadIdx.x;
    if (t < 2) ok[t] = 1;
    __syncthreads();
    bool vi = true, vf = true;
    for (int i = t; i < bound; i += 256) {
        const unsigned int d = hmap[i];
        vi = vi && (d == 0u || d == 1u);
        vf = vf && (d == 0u || d == 0x3f800000u);
    }
    if (!vi) atomicAnd(&ok[0], 0);
    if (!vf) atomicAnd(&ok[1], 0);
    for (int i = t; i < NSLOTS * 5; i += 256) acc[i] = 0.0;
    __syncthreads();
    if (t == 0) *flag = ok[0] ? 1 : (ok[1] ? 2 : 0);
}

// --- Kernel 2: 5-threads-per-cell streaming --------------------------------
// thread T=(cell,q): loads
//   noobj float2  pred[cell*30 + 2q]        (dense 24B-stride pattern)
//   cls 2x float2 pred[cell*30 + 10 + 4q]   (dense)
//   tc float4     tc[cell*20 + 4q]          (= byte 16*T: perfectly linear)
//   obj           hmap[cell]                (5-way L1 broadcast)
// q==0 additionally: tb float4, p[0..9] via LDS -> IoU/reg/conf.
__global__ __launch_bounds__(640) void yl_main(
    const float* __restrict__ pred, const float* __restrict__ tb,
    const float* __restrict__ tc, const void* __restrict__ hmap,
    const int* __restrict__ flag_p, double* __restrict__ acc, int cells)
{
    __shared__ float lp[128 * 10];   // p[0..9] per local cell
    __shared__ float red[10][5];

    const int tl = threadIdx.x;
    const int cl = tl / 5;           // local cell 0..127
    const int q  = tl - 5 * cl;      // 0..4
    const int cell = blockIdx.x * 128 + cl;

    float obj = 0.f, s_cls = 0.f, s_no = 0.f, s_reg = 0.f, s_conf = 0.f;
    float objsum = 0.f;

    if (cell < cells) {
        const int flag = *flag_p;    // uniform scalar
        if (flag == 1)      obj = (float)((const int*)hmap)[cell];
        else if (flag == 2) obj = ((const float*)hmap)[cell];
        else                obj = (float)((const unsigned char*)hmap)[cell];

        const float* pc = pred + (size_t)cell * 30;
        const float2 nb = *reinterpret_cast<const float2*>(pc + 2 * q);
        const float2 ca = *reinterpret_cast<const float2*>(pc + 10 + 4 * q);
        const float2 cb = *reinterpret_cast<const float2*>(pc + 12 + 4 * q);
        const float4 tcv = *reinterpret_cast<const float4*>(tc + (size_t)cell * 20 + 4 * q);

        *reinterpret_cast<float2*>(&lp[cl * 10 + 2 * q]) = nb;  // 2-way banks, free

        // no-object partial: (1-obj) * (p[2q]^2 + p[2q+1]^2), q=0..4 covers p[0..9]
        s_no = (1.f - obj) * (nb.x * nb.x + nb.y * nb.y);

        // class partial: j = 4q..4q+3
        const float d0 = ca.x - tcv.x, d1 = ca.y - tcv.y;
        const float d2 = cb.x - tcv.z, d3 = cb.y - tcv.w;
        s_cls = obj * (d0 * d0 + d1 * d1 + d2 * d2 + d3 * d3);
    }
    __syncthreads();

    if (q == 0 && cell < cells) {
        float p[10];
        #pragma unroll
        for (int k = 0; k < 10; ++k) p[k] = lp[cl * 10 + k];  // stride-10: conflict-free
        const float4 tbv = reinterpret_cast<const float4*>(tb)[cell];

        const float tx1 = tbv.x / 14.f - 0.5f * tbv.z, ty1 = tbv.y / 14.f - 0.5f * tbv.w;
        const float tx2 = tbv.x / 14.f + 0.5f * tbv.z, ty2 = tbv.y / 14.f + 0.5f * tbv.w;
        const float ta  = (tx2 - tx1) * (ty2 - ty1);

        auto iou_f = [&](float x, float y, float w, float h) -> float {
            const float x1 = x / 14.f - 0.5f * w, y1 = y / 14.f - 0.5f * h;
            const float x2 = x / 14.f + 0.5f * w, y2 = y / 14.f + 0.5f * h;
            const float lw = fmaxf(fminf(x2, tx2) - fmaxf(x1, tx1), 0.f);
            const float lh = fmaxf(fminf(y2, ty2) - fmaxf(y1, ty1), 0.f);
            const float inter = lw * lh;
            const float a = (x2 - x1) * (y2 - y1);
            return inter / (a + ta - inter);
        };
        const float iou1 = iou_f(p[0], p[1], p[2], p[3]);
        const float iou2 = iou_f(p[5], p[6], p[7], p[8]);

        const bool take1 = iou1 >= iou2;
        const float bx = take1 ? p[0] : p[5];
        const float by = take1 ? p[1] : p[6];
        const float bw = take1 ? p[2] : p[7];
        const float bh = take1 ? p[3] : p[8];
        const float bc = take1 ? p[4] : p[9];
        const float biou = take1 ? iou1 : iou2;

        const float dx = bx - tbv.x, dy = by - tbv.y;
        const float dw = sqrtf(bw) - sqrtf(tbv.z);
        const float dh = sqrtf(bh) - sqrtf(tbv.w);
        s_reg = obj * (dx * dx + dy * dy + dw * dw + dh * dh);
        const float dc = bc - biou;
        s_conf = obj * dc * dc;
        objsum = obj;                // count each cell once
    }

    // block reduction: wave64 shfl -> LDS across 10 waves -> spread atomics
    float vals[5] = {objsum, s_cls, s_no, s_reg, s_conf};
    #pragma unroll
    for (int i = 0; i < 5; ++i) {
        float v = vals[i];
        #pragma unroll
        for (int off = 32; off > 0; off >>= 1) v += __shfl_down(v, off);
        vals[i] = v;
    }
    const int lane = tl & 63, wid = tl >> 6;  // 10 waves
    if (lane == 0) {
        #pragma unroll
        for (int i = 0; i < 5; ++i) red[wid][i] = vals[i];
    }
    __syncthreads();
    if (tl < 5) {
        float s = 0.f;
        #pragma unroll
        for (int w = 0; w < 10; ++w) s += red[w][tl];
        atomicAdd(&acc[(blockIdx.x & (NSLOTS - 1)) * 5 + tl], (double)s);
    }
}

// --- Kernel 3: fold 64 slots, compute the 5 outputs -------------------------
__global__ void yl_finalize(const double* __restrict__ acc, float* __restrict__ out,
                            int cells, int nbatch) {
    const int t = threadIdx.x;  // 64 threads
    double v[5];
    #pragma unroll
    for (int i = 0; i < 5; ++i) v[i] = acc[t * 5 + i];
    #pragma unroll
    for (int i = 0; i < 5; ++i) {
        #pragma unroll
        for (int off = 32; off > 0; off >>= 1) v[i] += __shfl_down(v[i], off);
    }
    if (t == 0) {
        const double n_obj = v[0], n_noobj = (double)cells - v[0];
        const float reg_loss  = (float)(v[3] * 5.0 / n_obj);
        const float conf_loss = (float)(v[4] / n_obj);
        const float no_loss   = (float)(0.5 * v[2] / n_noobj);
        const float cls_loss  = (float)(v[1] / (double)nbatch);
        out[1] = reg_loss;
        out[2] = conf_loss;
        out[3] = no_loss;
        out[4] = cls_loss;
        out[0] = reg_loss + conf_loss + no_loss + cls_loss;  // fp32 add order = reference
    }
}

extern "C" void kernel_launch(void* const* d_in, const int* in_sizes, int n_in,
                              void* d_out, int out_size, void* d_ws, size_t ws_size,
                              hipStream_t stream) {
    const float* pred = (const float*)d_in[0];
    const float* tb   = (const float*)d_in[1];
    const float* tc   = (const float*)d_in[2];
    const void*  hm   = d_in[3];
    const int cells  = in_sizes[3];          // N * S * S
    const int nbatch = cells / 196;          // N (S=14)
    double* acc = (double*)d_ws;
    int* flag   = (int*)((char*)d_ws + NSLOTS * 5 * sizeof(double));

    const int bound = cells / 4 < 1024 ? cells / 4 : 1024;  // safe for all encodings
    yl_detect_zero<<<1, 256, 0, stream>>>((const unsigned int*)hm, acc, flag, bound);
    const int blocks = (cells + 127) / 128;   // 128 cells per 640-thread block
    yl_main<<<blocks, 640, 0, stream>>>(pred, tb, tc, hm, flag, acc, cells);
    yl_finalize<<<1, 64, 0, stream>>>(acc, (float*)d_out, cells, nbatch);
}